// Round 1
// baseline (282.212 us; speedup 1.0000x reference)
//
#include <hip/hip_runtime.h>
#include <stdint.h>

#define NBATCH 256
#define NQ 900
#define NC 91
#define NQC (NQ * NC)      // 81900
#define KSEL 100
#define NBINS 8192
#define NT 256
#define CHUNK (NBINS / NT) // 32
#define CAP 1024
#define IOU_THRF 0.7f
#define CONF_THRF 0.3f

union SMem {
  struct {
    uint32_t hist[NBINS];                // 32 KB
    unsigned long long cand[CAP];        // 8 KB
  } sel;
  struct {
    float iou[KSEL * KSEL];              // 40 KB
    float box[KSEL][4];
    int keep[KSEL];
  } nms;
};

__device__ __forceinline__ float sigmoidf_ref(float x) {
  // plain f32 1/(1+exp(-x)); no contraction hazard (add+div only)
  return 1.0f / (1.0f + expf(-x));
}

__global__ __launch_bounds__(NT) void postproc(const float* __restrict__ logits,
                                               const float* __restrict__ pboxes,
                                               const float* __restrict__ tsizes,
                                               float* __restrict__ out) {
  __shared__ SMem sm;
  __shared__ uint32_t chunk_sum[NT];
  __shared__ uint32_t s_cut, s_above, s_cnt, s_cut2;
  __shared__ uint32_t cand_cnt;

  const int b = blockIdx.x;
  const int tid = threadIdx.x;
  const float* lg = logits + (size_t)b * NQC;

  // ---------- pass 1: histogram of prob bits >> 17 ----------
  for (int i = tid; i < NBINS; i += NT) sm.sel.hist[i] = 0;
  __syncthreads();
  for (int i = tid; i < NQC; i += NT) {
    uint32_t bits = __float_as_uint(sigmoidf_ref(lg[i]));
    atomicAdd(&sm.sel.hist[bits >> 17], 1u);
  }
  __syncthreads();

  // ---------- find cut bin (bin containing the 100th largest) ----------
  {
    uint32_t s = 0;
    const int base = tid * CHUNK;
    for (int i = 0; i < CHUNK; i++) s += sm.sel.hist[base + i];
    chunk_sum[tid] = s;
  }
  __syncthreads();
  {
    uint32_t after = 0;
    for (int t = tid + 1; t < NT; t++) after += chunk_sum[t];
    const uint32_t mine = chunk_sum[tid];
    if (after < KSEL && after + mine >= KSEL) {  // exactly one thread
      uint32_t run = after;
      const int base = tid * CHUNK;
      for (int i = CHUNK - 1; i >= 0; i--) {
        uint32_t h = sm.sel.hist[base + i];
        if (run + h >= KSEL) { s_cut = (uint32_t)(base + i); s_above = run; s_cnt = h; break; }
        run += h;
      }
    }
  }
  __syncthreads();
  const uint32_t cut1 = s_cut;
  const bool need2 = (s_above + s_cnt > CAP);
  uint32_t cut2 = 0;

  // ---------- rare fallback: level-2 refine on bits[16:4] ----------
  if (need2) {
    const uint32_t above0 = s_above;
    __syncthreads();
    for (int i = tid; i < NBINS; i += NT) sm.sel.hist[i] = 0;
    __syncthreads();
    for (int i = tid; i < NQC; i += NT) {
      uint32_t bits = __float_as_uint(sigmoidf_ref(lg[i]));
      if ((bits >> 17) == cut1) atomicAdd(&sm.sel.hist[(bits >> 4) & 0x1FFFu], 1u);
    }
    __syncthreads();
    {
      uint32_t s = 0;
      const int base = tid * CHUNK;
      for (int i = 0; i < CHUNK; i++) s += sm.sel.hist[base + i];
      chunk_sum[tid] = s;
    }
    __syncthreads();
    {
      uint32_t after = 0;
      for (int t = tid + 1; t < NT; t++) after += chunk_sum[t];
      const uint32_t mine = chunk_sum[tid];
      if (above0 + after < KSEL && above0 + after + mine >= KSEL) {
        uint32_t run = above0 + after;
        const int base = tid * CHUNK;
        for (int i = CHUNK - 1; i >= 0; i--) {
          uint32_t h = sm.sel.hist[base + i];
          if (run + h >= KSEL) { s_cut2 = (uint32_t)(base + i); break; }
          run += h;
        }
      }
    }
    __syncthreads();
    cut2 = s_cut2;
  }

  // ---------- pass 2: collect candidates ----------
  if (tid == 0) cand_cnt = 0;
  __syncthreads();
  for (int i = tid; i < NQC; i += NT) {
    uint32_t bits = __float_as_uint(sigmoidf_ref(lg[i]));
    uint32_t b1 = bits >> 17;
    bool sel = need2 ? (b1 > cut1 || (b1 == cut1 && ((bits >> 4) & 0x1FFFu) >= cut2))
                     : (b1 >= cut1);
    if (sel) {
      uint32_t pos = atomicAdd(&cand_cnt, 1u);
      if (pos < CAP)
        sm.sel.cand[pos] =
            (((unsigned long long)(~bits)) << 32) | (unsigned long long)(uint32_t)i;
    }
  }
  __syncthreads();
  const uint32_t n = cand_cnt < CAP ? cand_cnt : CAP;
  uint32_t P = 1;
  while (P < n) P <<= 1;           // n >= 100 always, so P >= 128
  for (uint32_t i = n + tid; i < P; i += NT) sm.sel.cand[i] = ~0ULL;
  __syncthreads();

  // ---------- bitonic sort ascending: key = (~prob_bits)<<32 | idx ----------
  for (uint32_t kk = 2; kk <= P; kk <<= 1) {
    for (uint32_t jj = kk >> 1; jj > 0; jj >>= 1) {
      for (uint32_t i = tid; i < P; i += NT) {
        uint32_t ixj = i ^ jj;
        if (ixj > i) {
          unsigned long long a = sm.sel.cand[i];
          unsigned long long c = sm.sel.cand[ixj];
          bool sw = ((i & kk) == 0) ? (a > c) : (a < c);
          if (sw) { sm.sel.cand[i] = c; sm.sel.cand[ixj] = a; }
        }
      }
      __syncthreads();
    }
  }

  // ---------- extract top-100 to registers before union reuse ----------
  float score = 0.0f;
  int idx = 0;
  if (tid < KSEL) {
    unsigned long long key = sm.sel.cand[tid];
    score = __uint_as_float(~(uint32_t)(key >> 32));
    idx = (int)(uint32_t)(key & 0xFFFFFFFFu);
  }
  __syncthreads();  // all reads from sel done before nms overwrite

  const float img_h = tsizes[b * 2 + 0];
  const float img_w = tsizes[b * 2 + 1];
  float* out_scores = out;
  float* out_labels = out + (size_t)NBATCH * KSEL;
  float* out_boxes  = out + (size_t)2 * NBATCH * KSEL;
  float* out_keep   = out + (size_t)2 * NBATCH * KSEL + (size_t)NBATCH * KSEL * 4;

  if (tid < KSEL) {
    int q = idx / NC;
    int lab = idx - q * NC;
    const float* pb = pboxes + ((size_t)b * NQ + q) * 4;
    float cx = pb[0], cy = pb[1], w = pb[2], h = pb[3];
    // per-op IEEE f32, no FMA contraction (match numpy op order)
    float hw = __fmul_rn(0.5f, w), hh = __fmul_rn(0.5f, h);
    float x0 = __fmul_rn(__fsub_rn(cx, hw), img_w);
    float y0 = __fmul_rn(__fsub_rn(cy, hh), img_h);
    float x1 = __fmul_rn(__fadd_rn(cx, hw), img_w);
    float y1 = __fmul_rn(__fadd_rn(cy, hh), img_h);
    out_scores[(size_t)b * KSEL + tid] = score;
    out_labels[(size_t)b * KSEL + tid] = (float)lab;
    float* ob = out_boxes + ((size_t)b * KSEL + tid) * 4;
    ob[0] = x0; ob[1] = y0; ob[2] = x1; ob[3] = y1;
    sm.nms.box[tid][0] = x0; sm.nms.box[tid][1] = y0;
    sm.nms.box[tid][2] = x1; sm.nms.box[tid][3] = y1;
    sm.nms.keep[tid] = 1;
  }
  __syncthreads();

  // ---------- IoU matrix ----------
  for (int e = tid; e < KSEL * KSEL; e += NT) {
    int i = e / KSEL;
    int j = e - i * KSEL;
    float ax0 = sm.nms.box[i][0], ay0 = sm.nms.box[i][1];
    float ax1 = sm.nms.box[i][2], ay1 = sm.nms.box[i][3];
    float bx0 = sm.nms.box[j][0], by0 = sm.nms.box[j][1];
    float bx1 = sm.nms.box[j][2], by1 = sm.nms.box[j][3];
    float areaA = __fmul_rn(__fsub_rn(ax1, ax0), __fsub_rn(ay1, ay0));
    float areaB = __fmul_rn(__fsub_rn(bx1, bx0), __fsub_rn(by1, by0));
    float ltx = fmaxf(ax0, bx0), lty = fmaxf(ay0, by0);
    float rbx = fminf(ax1, bx1), rby = fminf(ay1, by1);
    float wx = fmaxf(__fsub_rn(rbx, ltx), 0.0f);
    float wy = fmaxf(__fsub_rn(rby, lty), 0.0f);
    float inter = __fmul_rn(wx, wy);
    float uni = __fsub_rn(__fadd_rn(areaA, areaB), inter);
    float iou = __fdiv_rn(inter, fmaxf(uni, 1e-9f));
    sm.nms.iou[e] = iou;
  }
  __syncthreads();

  // ---------- sequential NMS (exact fori_loop semantics) ----------
  for (int i = 0; i < KSEL; i++) {
    int ki = sm.nms.keep[i];
    if (ki && tid < KSEL && tid > i && sm.nms.iou[i * KSEL + tid] > IOU_THRF)
      sm.nms.keep[tid] = 0;
    __syncthreads();
  }

  if (tid < KSEL) {
    float kp = (score > CONF_THRF && sm.nms.keep[tid]) ? 1.0f : 0.0f;
    out_keep[(size_t)b * KSEL + tid] = kp;
  }
}

extern "C" void kernel_launch(void* const* d_in, const int* in_sizes, int n_in,
                              void* d_out, int out_size, void* d_ws, size_t ws_size,
                              hipStream_t stream) {
  const float* logits = (const float*)d_in[0];   // (256, 900, 91) f32
  const float* pboxes = (const float*)d_in[1];   // (256, 900, 4)  f32
  const float* tsizes = (const float*)d_in[2];   // (256, 2)       f32
  (void)in_sizes; (void)n_in; (void)out_size; (void)d_ws; (void)ws_size;
  postproc<<<NBATCH, NT, 0, stream>>>(logits, pboxes, tsizes, (float*)d_out);
}

// Round 2
// 63.135 us; speedup vs baseline: 4.4700x; 4.4700x over previous
//
#include <hip/hip_runtime.h>
#include <stdint.h>

#define NBATCH 256
#define NQ 900
#define NC 91
#define NQC (NQ * NC)      // 81900
#define NV4 (NQC / 4)      // 20475 float4s, exact
#define KSEL 100
#define NBINS 8192
#define NT 1024
#define CHUNK (NBINS / NT) // 8
#define CAP 1024
#define IOU_THRF 0.7f
#define CONF_THRF 0.3f

union SMem {
  struct {
    uint32_t hist[NBINS];                // 32 KB
    unsigned long long cand[CAP];        // 8 KB
  } sel;
  struct {
    float iou[KSEL * KSEL];              // 40 KB
    float box[KSEL][4];
    int keep[KSEL];
  } nms;
};

// monotone key: ascending uint order == ascending float order
__device__ __forceinline__ uint32_t fkey(float x) {
  uint32_t b = __float_as_uint(x);
  return b ^ ((uint32_t)((int32_t)b >> 31) | 0x80000000u);
}

__device__ __forceinline__ float sigmoidf_ref(float x) {
  return 1.0f / (1.0f + expf(-x));
}

__global__ __launch_bounds__(NT) void postproc(const float* __restrict__ logits,
                                               const float* __restrict__ pboxes,
                                               const float* __restrict__ tsizes,
                                               float* __restrict__ out) {
  __shared__ SMem sm;
  __shared__ uint32_t chunk_s[NT];
  __shared__ uint32_t suf[NT];
  __shared__ uint32_t s_cut, s_above, s_cnt, s_lobin, s_cut2;
  __shared__ uint32_t cand_cnt;

  const int b = blockIdx.x;
  const int tid = threadIdx.x;
  const float4* lg4 = (const float4*)(logits + (size_t)b * NQC);

  // ---------- pass 1: histogram of monotone logit keys (no expf) ----------
  for (int i = tid; i < NBINS; i += NT) sm.sel.hist[i] = 0;
  __syncthreads();
  for (int i = tid; i < NV4; i += NT) {
    float4 v = lg4[i];
    atomicAdd(&sm.sel.hist[fkey(v.x) >> 19], 1u);
    atomicAdd(&sm.sel.hist[fkey(v.y) >> 19], 1u);
    atomicAdd(&sm.sel.hist[fkey(v.z) >> 19], 1u);
    atomicAdd(&sm.sel.hist[fkey(v.w) >> 19], 1u);
  }
  __syncthreads();

  // ---------- find cut bin via parallel suffix scan ----------
  uint32_t mine;
  {
    uint32_t s = 0;
    const int base = tid * CHUNK;
    #pragma unroll
    for (int i = 0; i < CHUNK; i++) s += sm.sel.hist[base + i];
    mine = s;
    chunk_s[tid] = s;
    suf[tid] = s;
  }
  __syncthreads();
  for (int off = 1; off < NT; off <<= 1) {
    uint32_t v = suf[tid];
    if (tid + off < NT) v += suf[tid + off];
    __syncthreads();
    suf[tid] = v;
    __syncthreads();
  }
  {
    uint32_t after = suf[tid] - mine;   // total in strictly-higher chunks
    if (after < KSEL && after + mine >= KSEL) {  // exactly one thread
      uint32_t run = after;
      const int base = tid * CHUNK;
      for (int i = CHUNK - 1; i >= 0; i--) {
        uint32_t h = sm.sel.hist[base + i];
        if (run + h >= KSEL) {
          uint32_t cut = (uint32_t)(base + i);
          uint32_t below = (cut > 0) ? sm.sel.hist[cut - 1] : 0;
          s_cut = cut; s_above = run; s_cnt = h;
          // collect one safety bin below the cut when it fits (tie-proof)
          s_lobin = (cut > 0 && run + h + below <= CAP) ? cut - 1 : cut;
          break;
        }
        run += h;
      }
    }
  }
  __syncthreads();
  const uint32_t cut1 = s_cut;
  const uint32_t lobin = s_lobin;
  const bool need2 = (s_above + s_cnt > CAP);
  uint32_t cut2 = 0;

  // ---------- rare fallback: refine on next 13 key bits ----------
  if (need2) {
    const uint32_t above0 = s_above;
    __syncthreads();
    for (int i = tid; i < NBINS; i += NT) sm.sel.hist[i] = 0;
    __syncthreads();
    for (int i = tid; i < NV4; i += NT) {
      float4 v = lg4[i];
      float xs[4] = {v.x, v.y, v.z, v.w};
      #pragma unroll
      for (int c = 0; c < 4; c++) {
        uint32_t k = fkey(xs[c]);
        if ((k >> 19) == cut1) atomicAdd(&sm.sel.hist[(k >> 6) & 0x1FFFu], 1u);
      }
    }
    __syncthreads();
    {
      uint32_t s = 0;
      const int base = tid * CHUNK;
      #pragma unroll
      for (int i = 0; i < CHUNK; i++) s += sm.sel.hist[base + i];
      mine = s;
      suf[tid] = s;
    }
    __syncthreads();
    for (int off = 1; off < NT; off <<= 1) {
      uint32_t v = suf[tid];
      if (tid + off < NT) v += suf[tid + off];
      __syncthreads();
      suf[tid] = v;
      __syncthreads();
    }
    {
      uint32_t after = above0 + (suf[tid] - mine);
      if (after < KSEL && after + mine >= KSEL) {
        uint32_t run = after;
        const int base = tid * CHUNK;
        for (int i = CHUNK - 1; i >= 0; i--) {
          uint32_t h = sm.sel.hist[base + i];
          if (run + h >= KSEL) { s_cut2 = (uint32_t)(base + i); break; }
          run += h;
        }
      }
    }
    __syncthreads();
    cut2 = s_cut2;
  }

  // ---------- pass 2: collect candidates; sigmoid only for selected ----------
  if (tid == 0) cand_cnt = 0;
  __syncthreads();
  for (int i = tid; i < NV4; i += NT) {
    float4 v = lg4[i];
    float xs[4] = {v.x, v.y, v.z, v.w};
    #pragma unroll
    for (int c = 0; c < 4; c++) {
      uint32_t k = fkey(xs[c]);
      uint32_t b1 = k >> 19;
      bool sel = need2 ? (b1 > cut1 || (b1 == cut1 && ((k >> 6) & 0x1FFFu) >= cut2))
                       : (b1 >= lobin);
      if (sel) {
        uint32_t pbits = __float_as_uint(sigmoidf_ref(xs[c]));
        uint32_t pos = atomicAdd(&cand_cnt, 1u);
        if (pos < CAP)
          sm.sel.cand[pos] = (((unsigned long long)(~pbits)) << 32) |
                             (unsigned long long)(uint32_t)(4 * i + c);
      }
    }
  }
  __syncthreads();
  const uint32_t n = cand_cnt < CAP ? cand_cnt : CAP;
  uint32_t P = 1;
  while (P < n) P <<= 1;           // n >= 100 always
  for (uint32_t i = n + tid; i < P; i += NT) sm.sel.cand[i] = ~0ULL;
  __syncthreads();

  // ---------- bitonic sort ascending: key = (~prob_bits)<<32 | idx ----------
  for (uint32_t kk = 2; kk <= P; kk <<= 1) {
    for (uint32_t jj = kk >> 1; jj > 0; jj >>= 1) {
      for (uint32_t i = tid; i < P; i += NT) {
        uint32_t ixj = i ^ jj;
        if (ixj > i) {
          unsigned long long a = sm.sel.cand[i];
          unsigned long long c = sm.sel.cand[ixj];
          bool sw = ((i & kk) == 0) ? (a > c) : (a < c);
          if (sw) { sm.sel.cand[i] = c; sm.sel.cand[ixj] = a; }
        }
      }
      __syncthreads();
    }
  }

  // ---------- extract top-100 to registers before union reuse ----------
  float score = 0.0f;
  int idx = 0;
  if (tid < KSEL) {
    unsigned long long key = sm.sel.cand[tid];
    score = __uint_as_float(~(uint32_t)(key >> 32));
    idx = (int)(uint32_t)(key & 0xFFFFFFFFu);
  }
  __syncthreads();  // all reads from sel done before nms overwrite

  const float img_h = tsizes[b * 2 + 0];
  const float img_w = tsizes[b * 2 + 1];
  float* out_scores = out;
  float* out_labels = out + (size_t)NBATCH * KSEL;
  float* out_boxes  = out + (size_t)2 * NBATCH * KSEL;
  float* out_keep   = out + (size_t)2 * NBATCH * KSEL + (size_t)NBATCH * KSEL * 4;

  if (tid < KSEL) {
    int q = idx / NC;
    int lab = idx - q * NC;
    const float* pb = pboxes + ((size_t)b * NQ + q) * 4;
    float cx = pb[0], cy = pb[1], w = pb[2], h = pb[3];
    float hw = __fmul_rn(0.5f, w), hh = __fmul_rn(0.5f, h);
    float x0 = __fmul_rn(__fsub_rn(cx, hw), img_w);
    float y0 = __fmul_rn(__fsub_rn(cy, hh), img_h);
    float x1 = __fmul_rn(__fadd_rn(cx, hw), img_w);
    float y1 = __fmul_rn(__fadd_rn(cy, hh), img_h);
    out_scores[(size_t)b * KSEL + tid] = score;
    out_labels[(size_t)b * KSEL + tid] = (float)lab;
    float* ob = out_boxes + ((size_t)b * KSEL + tid) * 4;
    ob[0] = x0; ob[1] = y0; ob[2] = x1; ob[3] = y1;
    sm.nms.box[tid][0] = x0; sm.nms.box[tid][1] = y0;
    sm.nms.box[tid][2] = x1; sm.nms.box[tid][3] = y1;
  }
  __syncthreads();

  // ---------- IoU matrix ----------
  for (int e = tid; e < KSEL * KSEL; e += NT) {
    int i = e / KSEL;
    int j = e - i * KSEL;
    float ax0 = sm.nms.box[i][0], ay0 = sm.nms.box[i][1];
    float ax1 = sm.nms.box[i][2], ay1 = sm.nms.box[i][3];
    float bx0 = sm.nms.box[j][0], by0 = sm.nms.box[j][1];
    float bx1 = sm.nms.box[j][2], by1 = sm.nms.box[j][3];
    float areaA = __fmul_rn(__fsub_rn(ax1, ax0), __fsub_rn(ay1, ay0));
    float areaB = __fmul_rn(__fsub_rn(bx1, bx0), __fsub_rn(by1, by0));
    float ltx = fmaxf(ax0, bx0), lty = fmaxf(ay0, by0);
    float rbx = fminf(ax1, bx1), rby = fminf(ay1, by1);
    float wx = fmaxf(__fsub_rn(rbx, ltx), 0.0f);
    float wy = fmaxf(__fsub_rn(rby, lty), 0.0f);
    float inter = __fmul_rn(wx, wy);
    float uni = __fsub_rn(__fadd_rn(areaA, areaB), inter);
    sm.nms.iou[e] = __fdiv_rn(inter, fmaxf(uni, 1e-9f));
  }
  __syncthreads();

  // ---------- sequential NMS inside wave 0 (shfl, no block barriers) ----------
  if (tid < 64) {
    int keepA = 1;            // box tid
    int keepB = 1;            // box tid+64 (valid if tid+64 < KSEL)
    for (int i = 0; i < KSEL; i++) {
      int owner = i & 63;
      int ki = (i < 64) ? __shfl(keepA, owner) : __shfl(keepB, owner);
      if (ki) {
        if (tid > i && sm.nms.iou[i * KSEL + tid] > IOU_THRF) keepA = 0;
        int j = tid + 64;
        if (j < KSEL && j > i && sm.nms.iou[i * KSEL + j] > IOU_THRF) keepB = 0;
      }
    }
    sm.nms.keep[tid] = keepA;
    if (tid + 64 < KSEL) sm.nms.keep[tid + 64] = keepB;
  }
  __syncthreads();

  if (tid < KSEL) {
    float kp = (score > CONF_THRF && sm.nms.keep[tid]) ? 1.0f : 0.0f;
    out_keep[(size_t)b * KSEL + tid] = kp;
  }
}

extern "C" void kernel_launch(void* const* d_in, const int* in_sizes, int n_in,
                              void* d_out, int out_size, void* d_ws, size_t ws_size,
                              hipStream_t stream) {
  const float* logits = (const float*)d_in[0];   // (256, 900, 91) f32
  const float* pboxes = (const float*)d_in[1];   // (256, 900, 4)  f32
  const float* tsizes = (const float*)d_in[2];   // (256, 2)       f32
  (void)in_sizes; (void)n_in; (void)out_size; (void)d_ws; (void)ws_size;
  postproc<<<NBATCH, NT, 0, stream>>>(logits, pboxes, tsizes, (float*)d_out);
}